// Round 10
// baseline (1091.868 us; speedup 1.0000x reference)
//
#include <hip/hip_runtime.h>
#include <math.h>

typedef _Float16 f16;
typedef __attribute__((ext_vector_type(8))) _Float16 half8;
typedef __attribute__((ext_vector_type(4))) _Float16 half4;
typedef __attribute__((ext_vector_type(4))) float floatx4;

#define NB 8192

// ======================= weight conversion =======================
// Linear (swz==0): dst[u][n][k] = src[u*K*N + k*N + n] * scale
// Swizzled (swz==GM): dst piece (n, g') holds k-group g = g'^(n&swz), so that a
// linear lane-order global_load_lds lands XOR-swizzled data in LDS.
struct ConvJob { const float* src; f16* dst; int K; int N; int ucount; float scale; int swz; };
struct ConvJobs { ConvJob j[28]; };

__global__ void convert_w(ConvJobs JJ) {
    ConvJob jb = JJ.j[blockIdx.z];
    int u = blockIdx.x;
    if (u >= jb.ucount) return;
    __shared__ f16 tile[128 * 136];
    const int K = jb.K, N = jb.N;
    const int npad = N + 8;
    const int nsh = (N == 128) ? 7 : 6;
    const int ksh = (K == 128) ? 7 : 6;
    const float* src = jb.src + (size_t)u * K * N;
    for (int idx = threadIdx.x; idx < K * N; idx += 256) {
        int k = idx >> nsh, n = idx & (N - 1);
        tile[k * npad + n] = (f16)(src[idx] * jb.scale);
    }
    __syncthreads();
    f16* dst = jb.dst + (size_t)u * N * K;
    for (int idx = threadIdx.x; idx < N * K; idx += 256) {
        int n = idx >> ksh, rem = idx & (K - 1);
        int g2 = rem >> 3, jj = rem & 7;
        int g = jb.swz ? (g2 ^ (n & jb.swz)) : g2;
        int k = g * 8 + jj;
        dst[idx] = tile[k * npad + n];
    }
}

// ======================= weight composition (R6) =======================
// Two consecutive linear layers fold into one: out[n][k] = sum_m wl[n][m]*wo[m][k].
// Both inputs already carry their 1/sqrt(K) scales (converted layout W[n*128+k]).
struct CompJob { const f16* wo; const f16* wl; f16* out; int N; };
struct CompJobs { CompJob j[4]; };

__global__ void compose_w(CompJobs JJ) {
    CompJob jb = JJ.j[blockIdx.z];
    int n = blockIdx.x;
    if (n >= jb.N) return;
    int k = threadIdx.x;                       // 128 threads = K
    const f16* wo = jb.wo + k;                 // column k of Wo (row-stride 128)
    const f16* wl = jb.wl + (size_t)n * 128;   // row n of Wl
    float acc = 0.f;
    #pragma unroll 8
    for (int m = 0; m < 128; m++)
        acc += (float)wl[m] * (float)wo[(size_t)m * 128];
    jb.out[(size_t)n * 128 + k] = (f16)acc;
}

// ======================= x -> planar f16 =======================
__global__ void x_to_planes(const float* __restrict__ x, f16* s_p, f16* v0, f16* v1, f16* v2) {
    int t = blockIdx.x * 256 + threadIdx.x;
    if (t >= NB * 64) return;
    int b = t >> 6, u = t & 63;
    const float* xr = x + (size_t)b * 256;
    s_p[t] = (f16)xr[u];
    v0[t] = (f16)xr[64 + 3 * u + 0];
    v1[t] = (f16)xr[64 + 3 * u + 1];
    v2[t] = (f16)xr[64 + 3 * u + 2];
}

// ======================= tensor-product unit (R10: bound 3->4 for M=128) =======================
// out[b,w] = sum_u p[b,u] * sum_v q[b,v] * Wt[u][w][v]
// Schedule/geometry identical to the R7/R9-measured kernel (256 thr / 4 waves,
// 64rx32c per wave via 16x16x32, 2x16KB slabs, global_load_lds pre-swizzled,
// per-u stage->compute->__syncthreads, f16 out). R10: __launch_bounds__(256,4)
// for M=128 too — unified-file budget 512/4 = 128 >= 84 VGPR + 32 AGPR = 116,
// so no spill (bound 5's 102 is what spilled); LDS 32KB x 4 = 128 <= 160KB.
// Effect: 4 blocks/CU -> grid 1280 over 1024 slots = 1.25 rounds (was 1.67)
// and a 4th independent wave/SIMD feeding the MFMA pipe. R8's regression was
// the 32rx64c re-split (LDS-bound), not occupancy — split kept at 64rx32c.
struct TpJob { const f16* p; const f16* q; const f16* w; f16* out; int pstride; int qstride; };
struct TpJobs { TpJob j[10]; };

template <int M>
__launch_bounds__(256, 4)
__global__ void tp_unit(TpJobs JJ) {
    TpJob jb = JJ.j[blockIdx.z];
    constexpr int KC = M / 32;            // 32-wide k chunks
    constexpr int GM = M / 8 - 1;         // swizzle key mask
    constexpr int SLABH = 64 * M;         // halfs per col-half slab
    constexpr int PIECES = SLABH / 8;     // 16B pieces per slab
    constexpr int IPW = PIECES / 256;     // glds instrs per thread per stage
    constexpr int SLABFULL = 128 * M;     // halfs per full (128-col) slab
    __shared__ f16 w_lds[2][SLABH];
    const int tid = threadIdx.x, lane = tid & 63, wave = tid >> 6;
    const int wm = wave & 1, wn = wave >> 1;
    const int l15 = lane & 15, quad = lane >> 4;
    const int rowBase = blockIdx.x * 128;
    const int colBase = blockIdx.y * 64;

    {
        int id = blockIdx.x + (int)gridDim.x * (blockIdx.y + (int)gridDim.y * blockIdx.z);
        int ph = (id >> 8) % 3;
        for (int i = 0; i < ph; i++) __builtin_amdgcn_s_sleep(18);
    }

    // Q fragments: register-resident (A-operand source)
    half8 qf[4][KC];
    int prow[4];
    #pragma unroll
    for (int t = 0; t < 4; t++) {
        int row = rowBase + wm * 64 + t * 16 + l15;
        prow[t] = row;
        const f16* qr = jb.q + (size_t)row * jb.qstride;
        #pragma unroll
        for (int c = 0; c < KC; c++) qf[t][c] = *(const half8*)(qr + c * 32 + quad * 8);
    }
    floatx4 acc[4][2];
    #pragma unroll
    for (int a = 0; a < 4; a++)
        #pragma unroll
        for (int b = 0; b < 2; b++) acc[a][b] = (floatx4){0.f, 0.f, 0.f, 0.f};

    // B-frag swizzled read offsets (halfs); layout pre-swizzled by convert_w
    int rd_off[2][KC];
    #pragma unroll
    for (int nt = 0; nt < 2; nt++) {
        int nl = wn * 32 + nt * 16 + l15;
        #pragma unroll
        for (int c = 0; c < KC; c++) {
            int g = c * 4 + quad;
            rd_off[nt][c] = nl * M + ((g ^ (nl & GM)) << 3);
        }
    }

    // DMA staging: wave w handles pieces [w*PIECES/4 .. +PIECES/4)
    const int wpBase = wave * (PIECES / 4);
    const f16* wsrc0 = jb.w + (size_t)colBase * M + (size_t)(wpBase + lane) * 8;
    auto stage = [&](int u, int buf) {
        const f16* src = wsrc0 + (size_t)u * SLABFULL;
        f16* dst = &w_lds[buf][0] + (size_t)wpBase * 8;
        #pragma unroll
        for (int i = 0; i < IPW; i++) {
            __builtin_amdgcn_global_load_lds(
                (const __attribute__((address_space(1))) void*)(src + i * 64 * 8),
                (__attribute__((address_space(3))) void*)(dst + i * 64 * 8),
                16, 0, 0);
        }
    };

    stage(0, 0);
    __syncthreads();

    for (int uc = 0; uc < M / 8; uc++) {
        half8 pcur[4];
        #pragma unroll
        for (int t = 0; t < 4; t++)
            pcur[t] = *(const half8*)(jb.p + (size_t)prow[t] * jb.pstride + uc * 8);
        #pragma unroll
        for (int j = 0; j < 8; j++) {
            const int u = uc * 8 + j;
            const int cur = j & 1;           // compile-time slab index
            if (j != 7 || uc != M / 8 - 1) stage(u + 1, cur ^ 1);
            #pragma unroll
            for (int c = 0; c < KC; c++) {
                half8 af[4];
                #pragma unroll
                for (int t = 0; t < 4; t++) {
                    f16 pv = pcur[t][j];
                    half8 p8 = {pv, pv, pv, pv, pv, pv, pv, pv};
                    af[t] = qf[t][c] * p8;    // v_pk_mul_f16
                }
                __builtin_amdgcn_s_setprio(1);
                #pragma unroll
                for (int nt = 0; nt < 2; nt++) {
                    half8 bf = *(const half8*)&w_lds[cur][rd_off[nt][c]];
                    #pragma unroll
                    for (int t = 0; t < 4; t++)
                        acc[t][nt] = __builtin_amdgcn_mfma_f32_16x16x32_f16(af[t], bf, acc[t][nt], 0, 0, 0);
                }
                __builtin_amdgcn_s_setprio(0);
            }
            __syncthreads();
        }
    }
    // epilogue (verified C/D mapping: col=lane&15, row=quad*4+reg); f16 store
    #pragma unroll
    for (int t = 0; t < 4; t++)
        #pragma unroll
        for (int nt = 0; nt < 2; nt++) {
            int col = colBase + wn * 32 + nt * 16 + l15;
            f16* orow = jb.out + (size_t)(rowBase + wm * 64 + t * 16 + quad * 4) * 128 + col;
            #pragma unroll
            for (int r = 0; r < 4; r++) orow[(size_t)r * 128] = (f16)acc[t][nt][r];
        }
}

// ======================= generic small GEMM (64-row blocks) =======================
// out[b, n] = sum_k A[b,k]*(Amul? Amul[b,k]:1) * W[n*K + k], epilogue modes.
// If nred>0: A[b,k] = sum_i red_i[b*128 + k]  (f16 planes, stride 128)
struct SmallJob { const f16* A; const f16* W; char* out; int astride; int ostride;
                  int ocol; int cstride; int mode; int Njob; int ny;
                  const f16* Amul; int mstride;
                  const f16* red0; const f16* red1; const f16* red2; const f16* red3;
                  int nred; };
struct SmallJobs { SmallJob j[4]; };

template <int K>
__launch_bounds__(256, 4)
__global__ void small_gemm(SmallJobs JJ) {
    SmallJob jb = JJ.j[blockIdx.z];
    if ((int)blockIdx.y >= jb.ny) return;
    constexpr int KC = K / 32;
    constexpr int NP = K + 8;
    constexpr int PR = K / 8;
    constexpr int PPT = 128 * K / 8 / 256;
    __shared__ f16 w_lds[128 * NP];
    const int tid = threadIdx.x, lane = tid & 63, wave = tid >> 6;
    const int wm = wave & 1, wn = wave >> 1;
    const int l15 = lane & 15, quad = lane >> 4;
    const int rowBase = blockIdx.x * 64;     // 64-row blocks for CU coverage
    const int nBase = blockIdx.y * 128;

    #pragma unroll
    for (int t = 0; t < PPT; t++) {
        int idx = t * 256 + tid;
        int r = idx / PR, pc = idx % PR;
        int4 v = {0, 0, 0, 0};
        if (nBase + r < jb.Njob)
            v = *(const int4*)(jb.W + (size_t)(nBase + r) * K + pc * 8);
        *(int4*)&w_lds[r * NP + pc * 8] = v;
    }
    half8 qf[2][KC];
    for (int t = 0; t < 2; t++) {
        int row = rowBase + wm * 32 + t * 16 + l15;
        if (jb.nred) {
            #pragma unroll
            for (int c = 0; c < KC; c++) {
                size_t boff = (size_t)row * 128 + c * 32 + quad * 8;
                half8 s = *(const half8*)(jb.red0 + boff);
                if (jb.nred > 1) s = s + *(const half8*)(jb.red1 + boff);
                if (jb.nred > 2) s = s + *(const half8*)(jb.red2 + boff);
                if (jb.nred > 3) s = s + *(const half8*)(jb.red3 + boff);
                qf[t][c] = s;
            }
        } else {
            const f16* ar = jb.A + (size_t)row * jb.astride;
            #pragma unroll
            for (int c = 0; c < KC; c++) qf[t][c] = *(const half8*)(ar + c * 32 + quad * 8);
        }
        if (jb.Amul) {
            const f16* mr = jb.Amul + (size_t)row * jb.mstride;
            #pragma unroll
            for (int c = 0; c < KC; c++) qf[t][c] = qf[t][c] * *(const half8*)(mr + c * 32 + quad * 8);
        }
    }
    floatx4 acc[2][4];
    #pragma unroll
    for (int a = 0; a < 2; a++)
        #pragma unroll
        for (int b = 0; b < 4; b++) acc[a][b] = (floatx4){0.f, 0.f, 0.f, 0.f};
    __syncthreads();
    #pragma unroll
    for (int c = 0; c < KC; c++)
        #pragma unroll
        for (int nt = 0; nt < 4; nt++) {
            half8 bf = *(const half8*)&w_lds[(wn * 64 + nt * 16 + l15) * NP + c * 32 + quad * 8];
            #pragma unroll
            for (int t = 0; t < 2; t++)
                acc[t][nt] = __builtin_amdgcn_mfma_f32_16x16x32_f16(qf[t][c], bf, acc[t][nt], 0, 0, 0);
        }
    const float GAIN = 1.5927116870880127f;
    #pragma unroll
    for (int t = 0; t < 2; t++)
        #pragma unroll
        for (int nt = 0; nt < 4; nt++) {
            int col = nBase + wn * 64 + nt * 16 + l15;
            if (col >= jb.Njob) continue;
            int rowB = rowBase + wm * 32 + t * 16 + quad * 4;
            #pragma unroll
            for (int r = 0; r < 4; r++) {
                float v = acc[t][nt][r];
                size_t ro = (size_t)(rowB + r) * jb.ostride;
                if (jb.mode == 0)      ((f16*)jb.out)[ro + jb.ocol + col] = (f16)v;
                else if (jb.mode == 1) ((f16*)jb.out)[ro + jb.ocol + col] = (f16)(GAIN * tanhf(v));
                else                   ((float*)jb.out)[ro + jb.ocol + (size_t)col * jb.cstride] = v;
            }
        }
}

// ======================= host launcher =======================
extern "C" void kernel_launch(void* const* d_in, const int* in_sizes, int n_in,
                              void* d_out, int out_size, void* d_ws, size_t ws_size,
                              hipStream_t stream) {
    const float* x = (const float*)d_in[0];
    const float* W_IN[28];
    for (int i = 0; i < 28; i++) W_IN[i] = (const float*)d_in[1 + i];

    char* base = (char*)d_ws;
    size_t off = 0;
    auto alloc = [&](size_t bytes) -> char* {
        char* p = base + off;
        off += (bytes + 255) & ~(size_t)255;
        return p;
    };
    const size_t S128 = (size_t)NB * 128;

    f16* Wl12_b1_s = (f16*)alloc(8192 * 2);
    f16* Wl12_b1_v = (f16*)alloc(8192 * 2);
    f16* Wl12_b2_s = (f16*)alloc(32768 * 2);
    f16* Wl12_b2_v = (f16*)alloc(32768 * 2);
    f16* Wtp_b1[4]; for (int i = 0; i < 4; i++) Wtp_b1[i] = (f16*)alloc((size_t)64 * 128 * 64 * 2);
    f16* Wtp_b2[4]; for (int i = 0; i < 4; i++) Wtp_b2[i] = (f16*)alloc((size_t)128 * 128 * 128 * 2);
    f16* Wg_b1_sg = (f16*)alloc(32768 * 2);
    f16* Wg_b1_v  = (f16*)alloc(16384 * 2);
    f16* Wg_b2_sg = (f16*)alloc(32768 * 2);
    f16* Wg_b2_v  = (f16*)alloc(16384 * 2);
    f16* Wo_b1_s = (f16*)alloc(16384 * 2);
    f16* Wo_b1_v = (f16*)alloc(16384 * 2);
    f16* Wo_b2_s = (f16*)alloc(16384 * 2);
    f16* Wo_b2_v = (f16*)alloc(16384 * 2);
    f16* Wf_s = (f16*)alloc(8192 * 2);
    f16* Wf_v = (f16*)alloc(8192 * 2);
    // composed weights (R6): o-lin folded into the following linear layer
    f16* Wc_s_b12 = (f16*)alloc((size_t)256 * 128 * 2);  // Wo_b1_s @ Wl12_b2_s
    f16* Wc_v_b12 = (f16*)alloc((size_t)256 * 128 * 2);  // Wo_b1_v @ Wl12_b2_v
    f16* Wc_s_fin = (f16*)alloc((size_t)64 * 128 * 2);   // Wo_b2_s @ Wf_s
    f16* Wc_v_fin = (f16*)alloc((size_t)64 * 128 * 2);   // Wo_b2_v @ Wf_v
    f16* s_p = (f16*)alloc((size_t)NB * 64 * 2);
    f16* v_p[3]; for (int i = 0; i < 3; i++) v_p[i] = (f16*)alloc((size_t)NB * 64 * 2);
    f16* Breg = (f16*)alloc((size_t)4 * NB * 256 * 2);
    f16* Part = (f16*)alloc((size_t)10 * S128 * 2);
    f16* Ereg = (f16*)alloc((size_t)5 * S128 * 2);
    (void)ws_size; (void)in_sizes; (void)n_in; (void)out_size;

    const float c_l1 = 0.125f;
    const float c128 = 0.088388347648318447f;
    const float c1 = 1.0f / (64.0f * 1.4142135623730951f);
    const float c2 = 1.0f / (128.0f * 1.4142135623730951f);
    const float i3 = 0.57735026918962584f;

    ConvJobs CJ;
    int jn = 0;
    auto CV = [&](const float* s, f16* d, int K, int N, int uc, float sc, int swz) {
        CJ.j[jn++] = ConvJob{s, d, K, N, uc, sc, swz};
    };
    CV(W_IN[0], Wl12_b1_s, 64, 64, 1, c_l1, 0);  CV(W_IN[2], Wl12_b1_s + 4096, 64, 64, 1, c_l1, 0);
    CV(W_IN[1], Wl12_b1_v, 64, 64, 1, c_l1, 0);  CV(W_IN[3], Wl12_b1_v + 4096, 64, 64, 1, c_l1, 0);
    CV(W_IN[13], Wl12_b2_s, 128, 128, 1, c128, 0); CV(W_IN[15], Wl12_b2_s + 16384, 128, 128, 1, c128, 0);
    CV(W_IN[14], Wl12_b2_v, 128, 128, 1, c128, 0); CV(W_IN[16], Wl12_b2_v + 16384, 128, 128, 1, c128, 0);
    CV(W_IN[4], Wtp_b1[0], 64, 128, 64, c1, 7);  CV(W_IN[5], Wtp_b1[1], 64, 128, 64, c1 * i3, 7);
    CV(W_IN[6], Wtp_b1[2], 64, 128, 64, c1, 7);  CV(W_IN[7], Wtp_b1[3], 64, 128, 64, c1, 7);
    CV(W_IN[17], Wtp_b2[0], 128, 128, 128, c2, 15); CV(W_IN[18], Wtp_b2[1], 128, 128, 128, c2 * i3, 15);
    CV(W_IN[19], Wtp_b2[2], 128, 128, 128, c2, 15); CV(W_IN[20], Wtp_b2[3], 128, 128, 128, c2, 15);
    CV(W_IN[8], Wg_b1_sg, 128, 128, 1, c128, 0);  CV(W_IN[9], Wg_b1_sg + 16384, 128, 128, 1, c128, 0);
    CV(W_IN[10], Wg_b1_v, 128, 128, 1, c128, 0);
    CV(W_IN[21], Wg_b2_sg, 128, 128, 1, c128, 0); CV(W_IN[22], Wg_b2_sg + 16384, 128, 128, 1, c128, 0);
    CV(W_IN[23], Wg_b2_v, 128, 128, 1, c128, 0);
    CV(W_IN[11], Wo_b1_s, 128, 128, 1, c128, 0);  CV(W_IN[12], Wo_b1_v, 128, 128, 1, c128, 0);
    CV(W_IN[24], Wo_b2_s, 128, 128, 1, c128, 0);  CV(W_IN[25], Wo_b2_v, 128, 128, 1, c128, 0);
    CV(W_IN[26], Wf_s, 128, 64, 1, c128, 0);      CV(W_IN[27], Wf_v, 128, 64, 1, c128, 0);
    convert_w<<<dim3(128, 1, 28), 256, 0, stream>>>(CJ);

    // compose folded weights (depends on convert_w; stream-ordered)
    {
        CompJobs CJ2;
        CJ2.j[0] = CompJob{Wo_b1_s, Wl12_b2_s, Wc_s_b12, 256};
        CJ2.j[1] = CompJob{Wo_b1_v, Wl12_b2_v, Wc_v_b12, 256};
        CJ2.j[2] = CompJob{Wo_b2_s, Wf_s, Wc_s_fin, 64};
        CJ2.j[3] = CompJob{Wo_b2_v, Wf_v, Wc_v_fin, 64};
        compose_w<<<dim3(256, 1, 4), 128, 0, stream>>>(CJ2);
    }

    x_to_planes<<<NB * 64 / 256, 256, 0, stream>>>(x, s_p, v_p[0], v_p[1], v_p[2]);

    auto SJ = [](const f16* A, const f16* W, void* out, int as, int os, int oc, int cs,
                 int mode, int Nj, int ny, const f16* Amul, int ms) {
        return SmallJob{A, W, (char*)out, as, os, oc, cs, mode, Nj, ny, Amul, ms,
                        nullptr, nullptr, nullptr, nullptr, 0};
    };

    f16* s12 = Breg;
    f16* v12[3]; for (int i = 0; i < 3; i++) v12[i] = Breg + (size_t)(1 + i) * NB * 128;
    f16* sg_gg = Ereg;
    f16* vl[3]; for (int i = 0; i < 3; i++) vl[i] = Ereg + 2 * S128 + i * S128;

    // ---- b1 l1+l2 ----
    {
        SmallJobs J;
        J.j[0] = SJ(s_p, Wl12_b1_s, s12, 64, 128, 0, 1, 0, 128, 1, nullptr, 0);
        for (int i = 0; i < 3; i++) J.j[1 + i] = SJ(v_p[i], Wl12_b1_v, v12[i], 64, 128, 0, 1, 0, 128, 1, nullptr, 0);
        small_gemm<64><<<dim3(128, 1, 4), 256, 0, stream>>>(J);
    }
    // ---- b1 tensor product ----
    {
        TpJobs J;
        J.j[0] = TpJob{s12, s12 + 64, Wtp_b1[0], Part + 0 * S128, 128, 128};
        for (int i = 0; i < 3; i++) J.j[1 + i] = TpJob{v12[i], v12[i] + 64, Wtp_b1[1], Part + (1 + i) * S128, 128, 128};
        for (int i = 0; i < 3; i++) J.j[4 + i] = TpJob{s12, v12[i] + 64, Wtp_b1[2], Part + (4 + i) * S128, 128, 128};
        for (int i = 0; i < 3; i++) J.j[7 + i] = TpJob{v12[i], s12 + 64, Wtp_b1[3], Part + (7 + i) * S128, 128, 128};
        tp_unit<64><<<dim3(64, 2, 10), 256, 0, stream>>>(J);
    }
    // ---- b1 gate (tp_reduce fused into A-load) ----
    {
        SmallJobs J;
        J.j[0] = SmallJob{nullptr, Wg_b1_sg, (char*)sg_gg, 128, 256, 0, 1, 1, 256, 2, nullptr, 0,
                          Part + 0 * S128, Part + 1 * S128, Part + 2 * S128, Part + 3 * S128, 4};
        for (int i = 0; i < 3; i++)
            J.j[1 + i] = SmallJob{nullptr, Wg_b1_v, (char*)vl[i], 128, 128, 0, 1, 0, 128, 1, nullptr, 0,
                                  Part + (4 + i) * S128, Part + (7 + i) * S128, nullptr, nullptr, 2};
        small_gemm<128><<<dim3(128, 2, 4), 256, 0, stream>>>(J);
    }
    f16* s12b = Breg;
    f16* v12b[3]; for (int i = 0; i < 3; i++) v12b[i] = Breg + (size_t)(1 + i) * NB * 256;
    // ---- b1 o-lin + b2 l1+l2, folded via composed weights (R6) ----
    {
        SmallJobs J;
        J.j[0] = SJ(sg_gg, Wc_s_b12, s12b, 256, 256, 0, 1, 0, 256, 2, nullptr, 0);
        for (int i = 0; i < 3; i++)
            J.j[1 + i] = SJ(vl[i], Wc_v_b12, v12b[i], 128, 256, 0, 1, 0, 256, 2, sg_gg + 128, 256);
        small_gemm<128><<<dim3(128, 2, 4), 256, 0, stream>>>(J);
    }
    // ---- b2 tensor product ----
    {
        TpJobs J;
        J.j[0] = TpJob{s12b, s12b + 128, Wtp_b2[0], Part + 0 * S128, 256, 256};
        for (int i = 0; i < 3; i++) J.j[1 + i] = TpJob{v12b[i], v12b[i] + 128, Wtp_b2[1], Part + (1 + i) * S128, 256, 256};
        for (int i = 0; i < 3; i++) J.j[4 + i] = TpJob{s12b, v12b[i] + 128, Wtp_b2[2], Part + (4 + i) * S128, 256, 256};
        for (int i = 0; i < 3; i++) J.j[7 + i] = TpJob{v12b[i], s12b + 128, Wtp_b2[3], Part + (7 + i) * S128, 256, 256};
        tp_unit<128><<<dim3(64, 2, 10), 256, 0, stream>>>(J);
    }
    // ---- b2 gate (tp_reduce fused) ----
    {
        SmallJobs J;
        J.j[0] = SmallJob{nullptr, Wg_b2_sg, (char*)sg_gg, 128, 256, 0, 1, 1, 256, 2, nullptr, 0,
                          Part + 0 * S128, Part + 1 * S128, Part + 2 * S128, Part + 3 * S128, 4};
        for (int i = 0; i < 3; i++)
            J.j[1 + i] = SmallJob{nullptr, Wg_b2_v, (char*)vl[i], 128, 128, 0, 1, 0, 128, 1, nullptr, 0,
                                  Part + (4 + i) * S128, Part + (7 + i) * S128, nullptr, nullptr, 2};
        small_gemm<128><<<dim3(128, 2, 4), 256, 0, stream>>>(J);
    }
    // ---- b2 o-lin + final lin, folded via composed weights -> d_out ----
    {
        SmallJobs J;
        J.j[0] = SJ(sg_gg, Wc_s_fin, d_out, 256, 256, 0, 1, 2, 64, 1, nullptr, 0);
        for (int i = 0; i < 3; i++)
            J.j[1 + i] = SJ(vl[i], Wc_v_fin, d_out, 128, 256, 64 + i, 3, 2, 64, 1, sg_gg + 128, 256);
        small_gemm<128><<<dim3(128, 1, 4), 256, 0, stream>>>(J);
    }
}

// Round 11
// 604.962 us; speedup vs baseline: 1.8049x; 1.8049x over previous
//
#include <hip/hip_runtime.h>
#include <math.h>

typedef _Float16 f16;
typedef __attribute__((ext_vector_type(8))) _Float16 half8;
typedef __attribute__((ext_vector_type(4))) _Float16 half4;
typedef __attribute__((ext_vector_type(4))) float floatx4;

#define NB 8192

// ======================= weight conversion =======================
// Linear (swz==0): dst[u][n][k] = src[u*K*N + k*N + n] * scale
// Swizzled (swz==GM): dst piece (n, g') holds k-group g = g'^(n&swz), so that a
// linear lane-order global_load_lds lands XOR-swizzled data in LDS.
struct ConvJob { const float* src; f16* dst; int K; int N; int ucount; float scale; int swz; };
struct ConvJobs { ConvJob j[28]; };

__global__ void convert_w(ConvJobs JJ) {
    ConvJob jb = JJ.j[blockIdx.z];
    int u = blockIdx.x;
    if (u >= jb.ucount) return;
    __shared__ f16 tile[128 * 136];
    const int K = jb.K, N = jb.N;
    const int npad = N + 8;
    const int nsh = (N == 128) ? 7 : 6;
    const int ksh = (K == 128) ? 7 : 6;
    const float* src = jb.src + (size_t)u * K * N;
    for (int idx = threadIdx.x; idx < K * N; idx += 256) {
        int k = idx >> nsh, n = idx & (N - 1);
        tile[k * npad + n] = (f16)(src[idx] * jb.scale);
    }
    __syncthreads();
    f16* dst = jb.dst + (size_t)u * N * K;
    for (int idx = threadIdx.x; idx < N * K; idx += 256) {
        int n = idx >> ksh, rem = idx & (K - 1);
        int g2 = rem >> 3, jj = rem & 7;
        int g = jb.swz ? (g2 ^ (n & jb.swz)) : g2;
        int k = g * 8 + jj;
        dst[idx] = tile[k * npad + n];
    }
}

// ======================= weight composition (R6) =======================
// Two consecutive linear layers fold into one: out[n][k] = sum_m wl[n][m]*wo[m][k].
// Both inputs already carry their 1/sqrt(K) scales (converted layout W[n*128+k]).
struct CompJob { const f16* wo; const f16* wl; f16* out; int N; };
struct CompJobs { CompJob j[4]; };

__global__ void compose_w(CompJobs JJ) {
    CompJob jb = JJ.j[blockIdx.z];
    int n = blockIdx.x;
    if (n >= jb.N) return;
    int k = threadIdx.x;                       // 128 threads = K
    const f16* wo = jb.wo + k;                 // column k of Wo (row-stride 128)
    const f16* wl = jb.wl + (size_t)n * 128;   // row n of Wl
    float acc = 0.f;
    #pragma unroll 8
    for (int m = 0; m < 128; m++)
        acc += (float)wl[m] * (float)wo[(size_t)m * 128];
    jb.out[(size_t)n * 128 + k] = (f16)acc;
}

// ======================= x -> planar f16 =======================
__global__ void x_to_planes(const float* __restrict__ x, f16* s_p, f16* v0, f16* v1, f16* v2) {
    int t = blockIdx.x * 256 + threadIdx.x;
    if (t >= NB * 64) return;
    int b = t >> 6, u = t & 63;
    const float* xr = x + (size_t)b * 256;
    s_p[t] = (f16)xr[u];
    v0[t] = (f16)xr[64 + 3 * u + 0];
    v1[t] = (f16)xr[64 + 3 * u + 1];
    v2[t] = (f16)xr[64 + 3 * u + 2];
}

// ======================= tensor-product unit (R9-measured optimum, restored) =======================
// out[b,w] = sum_u p[b,u] * sum_v q[b,v] * Wt[u][w][v]
// 256 thr / 4 waves, 64rx32c per wave via 16x16x32, 2x16KB LDS slabs,
// global_load_lds pre-swizzled, per-u stage->compute->__syncthreads, startup
// stagger, f16 out. Design space fully bounded this session:
//  - scheduling: counted-vmcnt, setprio, stagger, rotation -> ~305us attractor
//  - geometry: 32x32 shape, 32rx64c, 64rx64c -> LDS-bound or residency-starved
//  - occupancy: bound 3 optimal; bound 4 (R10) halves VGPR file -> qf spills,
//    FETCH x11, 2.6x slower; bound 5 spills too (R0).
// bound (M==128)?3:4 is the measured optimum. Do not change without new evidence.
struct TpJob { const f16* p; const f16* q; const f16* w; f16* out; int pstride; int qstride; };
struct TpJobs { TpJob j[10]; };

template <int M>
__launch_bounds__(256, (M == 128) ? 3 : 4)
__global__ void tp_unit(TpJobs JJ) {
    TpJob jb = JJ.j[blockIdx.z];
    constexpr int KC = M / 32;            // 32-wide k chunks
    constexpr int GM = M / 8 - 1;         // swizzle key mask
    constexpr int SLABH = 64 * M;         // halfs per col-half slab
    constexpr int PIECES = SLABH / 8;     // 16B pieces per slab
    constexpr int IPW = PIECES / 256;     // glds instrs per thread per stage
    constexpr int SLABFULL = 128 * M;     // halfs per full (128-col) slab
    __shared__ f16 w_lds[2][SLABH];
    const int tid = threadIdx.x, lane = tid & 63, wave = tid >> 6;
    const int wm = wave & 1, wn = wave >> 1;
    const int l15 = lane & 15, quad = lane >> 4;
    const int rowBase = blockIdx.x * 128;
    const int colBase = blockIdx.y * 64;

    {
        int id = blockIdx.x + (int)gridDim.x * (blockIdx.y + (int)gridDim.y * blockIdx.z);
        int ph = (id >> 8) % 3;
        for (int i = 0; i < ph; i++) __builtin_amdgcn_s_sleep(18);
    }

    // Q fragments: register-resident (A-operand source)
    half8 qf[4][KC];
    int prow[4];
    #pragma unroll
    for (int t = 0; t < 4; t++) {
        int row = rowBase + wm * 64 + t * 16 + l15;
        prow[t] = row;
        const f16* qr = jb.q + (size_t)row * jb.qstride;
        #pragma unroll
        for (int c = 0; c < KC; c++) qf[t][c] = *(const half8*)(qr + c * 32 + quad * 8);
    }
    floatx4 acc[4][2];
    #pragma unroll
    for (int a = 0; a < 4; a++)
        #pragma unroll
        for (int b = 0; b < 2; b++) acc[a][b] = (floatx4){0.f, 0.f, 0.f, 0.f};

    // B-frag swizzled read offsets (halfs); layout pre-swizzled by convert_w
    int rd_off[2][KC];
    #pragma unroll
    for (int nt = 0; nt < 2; nt++) {
        int nl = wn * 32 + nt * 16 + l15;
        #pragma unroll
        for (int c = 0; c < KC; c++) {
            int g = c * 4 + quad;
            rd_off[nt][c] = nl * M + ((g ^ (nl & GM)) << 3);
        }
    }

    // DMA staging: wave w handles pieces [w*PIECES/4 .. +PIECES/4)
    const int wpBase = wave * (PIECES / 4);
    const f16* wsrc0 = jb.w + (size_t)colBase * M + (size_t)(wpBase + lane) * 8;
    auto stage = [&](int u, int buf) {
        const f16* src = wsrc0 + (size_t)u * SLABFULL;
        f16* dst = &w_lds[buf][0] + (size_t)wpBase * 8;
        #pragma unroll
        for (int i = 0; i < IPW; i++) {
            __builtin_amdgcn_global_load_lds(
                (const __attribute__((address_space(1))) void*)(src + i * 64 * 8),
                (__attribute__((address_space(3))) void*)(dst + i * 64 * 8),
                16, 0, 0);
        }
    };

    stage(0, 0);
    __syncthreads();

    for (int uc = 0; uc < M / 8; uc++) {
        half8 pcur[4];
        #pragma unroll
        for (int t = 0; t < 4; t++)
            pcur[t] = *(const half8*)(jb.p + (size_t)prow[t] * jb.pstride + uc * 8);
        #pragma unroll
        for (int j = 0; j < 8; j++) {
            const int u = uc * 8 + j;
            const int cur = j & 1;           // compile-time slab index
            if (j != 7 || uc != M / 8 - 1) stage(u + 1, cur ^ 1);
            #pragma unroll
            for (int c = 0; c < KC; c++) {
                half8 af[4];
                #pragma unroll
                for (int t = 0; t < 4; t++) {
                    f16 pv = pcur[t][j];
                    half8 p8 = {pv, pv, pv, pv, pv, pv, pv, pv};
                    af[t] = qf[t][c] * p8;    // v_pk_mul_f16
                }
                __builtin_amdgcn_s_setprio(1);
                #pragma unroll
                for (int nt = 0; nt < 2; nt++) {
                    half8 bf = *(const half8*)&w_lds[cur][rd_off[nt][c]];
                    #pragma unroll
                    for (int t = 0; t < 4; t++)
                        acc[t][nt] = __builtin_amdgcn_mfma_f32_16x16x32_f16(af[t], bf, acc[t][nt], 0, 0, 0);
                }
                __builtin_amdgcn_s_setprio(0);
            }
            __syncthreads();
        }
    }
    // epilogue (verified C/D mapping: col=lane&15, row=quad*4+reg); f16 store
    #pragma unroll
    for (int t = 0; t < 4; t++)
        #pragma unroll
        for (int nt = 0; nt < 2; nt++) {
            int col = colBase + wn * 32 + nt * 16 + l15;
            f16* orow = jb.out + (size_t)(rowBase + wm * 64 + t * 16 + quad * 4) * 128 + col;
            #pragma unroll
            for (int r = 0; r < 4; r++) orow[(size_t)r * 128] = (f16)acc[t][nt][r];
        }
}

// ======================= generic small GEMM (64-row blocks) =======================
// out[b, n] = sum_k A[b,k]*(Amul? Amul[b,k]:1) * W[n*K + k], epilogue modes.
// If nred>0: A[b,k] = sum_i red_i[b*128 + k]  (f16 planes, stride 128)
struct SmallJob { const f16* A; const f16* W; char* out; int astride; int ostride;
                  int ocol; int cstride; int mode; int Njob; int ny;
                  const f16* Amul; int mstride;
                  const f16* red0; const f16* red1; const f16* red2; const f16* red3;
                  int nred; };
struct SmallJobs { SmallJob j[4]; };

template <int K>
__launch_bounds__(256, 4)
__global__ void small_gemm(SmallJobs JJ) {
    SmallJob jb = JJ.j[blockIdx.z];
    if ((int)blockIdx.y >= jb.ny) return;
    constexpr int KC = K / 32;
    constexpr int NP = K + 8;
    constexpr int PR = K / 8;
    constexpr int PPT = 128 * K / 8 / 256;
    __shared__ f16 w_lds[128 * NP];
    const int tid = threadIdx.x, lane = tid & 63, wave = tid >> 6;
    const int wm = wave & 1, wn = wave >> 1;
    const int l15 = lane & 15, quad = lane >> 4;
    const int rowBase = blockIdx.x * 64;     // 64-row blocks for CU coverage
    const int nBase = blockIdx.y * 128;

    #pragma unroll
    for (int t = 0; t < PPT; t++) {
        int idx = t * 256 + tid;
        int r = idx / PR, pc = idx % PR;
        int4 v = {0, 0, 0, 0};
        if (nBase + r < jb.Njob)
            v = *(const int4*)(jb.W + (size_t)(nBase + r) * K + pc * 8);
        *(int4*)&w_lds[r * NP + pc * 8] = v;
    }
    half8 qf[2][KC];
    for (int t = 0; t < 2; t++) {
        int row = rowBase + wm * 32 + t * 16 + l15;
        if (jb.nred) {
            #pragma unroll
            for (int c = 0; c < KC; c++) {
                size_t boff = (size_t)row * 128 + c * 32 + quad * 8;
                half8 s = *(const half8*)(jb.red0 + boff);
                if (jb.nred > 1) s = s + *(const half8*)(jb.red1 + boff);
                if (jb.nred > 2) s = s + *(const half8*)(jb.red2 + boff);
                if (jb.nred > 3) s = s + *(const half8*)(jb.red3 + boff);
                qf[t][c] = s;
            }
        } else {
            const f16* ar = jb.A + (size_t)row * jb.astride;
            #pragma unroll
            for (int c = 0; c < KC; c++) qf[t][c] = *(const half8*)(ar + c * 32 + quad * 8);
        }
        if (jb.Amul) {
            const f16* mr = jb.Amul + (size_t)row * jb.mstride;
            #pragma unroll
            for (int c = 0; c < KC; c++) qf[t][c] = qf[t][c] * *(const half8*)(mr + c * 32 + quad * 8);
        }
    }
    floatx4 acc[2][4];
    #pragma unroll
    for (int a = 0; a < 2; a++)
        #pragma unroll
        for (int b = 0; b < 4; b++) acc[a][b] = (floatx4){0.f, 0.f, 0.f, 0.f};
    __syncthreads();
    #pragma unroll
    for (int c = 0; c < KC; c++)
        #pragma unroll
        for (int nt = 0; nt < 4; nt++) {
            half8 bf = *(const half8*)&w_lds[(wn * 64 + nt * 16 + l15) * NP + c * 32 + quad * 8];
            #pragma unroll
            for (int t = 0; t < 2; t++)
                acc[t][nt] = __builtin_amdgcn_mfma_f32_16x16x32_f16(qf[t][c], bf, acc[t][nt], 0, 0, 0);
        }
    const float GAIN = 1.5927116870880127f;
    #pragma unroll
    for (int t = 0; t < 2; t++)
        #pragma unroll
        for (int nt = 0; nt < 4; nt++) {
            int col = nBase + wn * 64 + nt * 16 + l15;
            if (col >= jb.Njob) continue;
            int rowB = rowBase + wm * 32 + t * 16 + quad * 4;
            #pragma unroll
            for (int r = 0; r < 4; r++) {
                float v = acc[t][nt][r];
                size_t ro = (size_t)(rowB + r) * jb.ostride;
                if (jb.mode == 0)      ((f16*)jb.out)[ro + jb.ocol + col] = (f16)v;
                else if (jb.mode == 1) ((f16*)jb.out)[ro + jb.ocol + col] = (f16)(GAIN * tanhf(v));
                else                   ((float*)jb.out)[ro + jb.ocol + (size_t)col * jb.cstride] = v;
            }
        }
}

// ======================= host launcher =======================
extern "C" void kernel_launch(void* const* d_in, const int* in_sizes, int n_in,
                              void* d_out, int out_size, void* d_ws, size_t ws_size,
                              hipStream_t stream) {
    const float* x = (const float*)d_in[0];
    const float* W_IN[28];
    for (int i = 0; i < 28; i++) W_IN[i] = (const float*)d_in[1 + i];

    char* base = (char*)d_ws;
    size_t off = 0;
    auto alloc = [&](size_t bytes) -> char* {
        char* p = base + off;
        off += (bytes + 255) & ~(size_t)255;
        return p;
    };
    const size_t S128 = (size_t)NB * 128;

    f16* Wl12_b1_s = (f16*)alloc(8192 * 2);
    f16* Wl12_b1_v = (f16*)alloc(8192 * 2);
    f16* Wl12_b2_s = (f16*)alloc(32768 * 2);
    f16* Wl12_b2_v = (f16*)alloc(32768 * 2);
    f16* Wtp_b1[4]; for (int i = 0; i < 4; i++) Wtp_b1[i] = (f16*)alloc((size_t)64 * 128 * 64 * 2);
    f16* Wtp_b2[4]; for (int i = 0; i < 4; i++) Wtp_b2[i] = (f16*)alloc((size_t)128 * 128 * 128 * 2);
    f16* Wg_b1_sg = (f16*)alloc(32768 * 2);
    f16* Wg_b1_v  = (f16*)alloc(16384 * 2);
    f16* Wg_b2_sg = (f16*)alloc(32768 * 2);
    f16* Wg_b2_v  = (f16*)alloc(16384 * 2);
    f16* Wo_b1_s = (f16*)alloc(16384 * 2);
    f16* Wo_b1_v = (f16*)alloc(16384 * 2);
    f16* Wo_b2_s = (f16*)alloc(16384 * 2);
    f16* Wo_b2_v = (f16*)alloc(16384 * 2);
    f16* Wf_s = (f16*)alloc(8192 * 2);
    f16* Wf_v = (f16*)alloc(8192 * 2);
    // composed weights (R6): o-lin folded into the following linear layer
    f16* Wc_s_b12 = (f16*)alloc((size_t)256 * 128 * 2);  // Wo_b1_s @ Wl12_b2_s
    f16* Wc_v_b12 = (f16*)alloc((size_t)256 * 128 * 2);  // Wo_b1_v @ Wl12_b2_v
    f16* Wc_s_fin = (f16*)alloc((size_t)64 * 128 * 2);   // Wo_b2_s @ Wf_s
    f16* Wc_v_fin = (f16*)alloc((size_t)64 * 128 * 2);   // Wo_b2_v @ Wf_v
    f16* s_p = (f16*)alloc((size_t)NB * 64 * 2);
    f16* v_p[3]; for (int i = 0; i < 3; i++) v_p[i] = (f16*)alloc((size_t)NB * 64 * 2);
    f16* Breg = (f16*)alloc((size_t)4 * NB * 256 * 2);
    f16* Part = (f16*)alloc((size_t)10 * S128 * 2);
    f16* Ereg = (f16*)alloc((size_t)5 * S128 * 2);
    (void)ws_size; (void)in_sizes; (void)n_in; (void)out_size;

    const float c_l1 = 0.125f;
    const float c128 = 0.088388347648318447f;
    const float c1 = 1.0f / (64.0f * 1.4142135623730951f);
    const float c2 = 1.0f / (128.0f * 1.4142135623730951f);
    const float i3 = 0.57735026918962584f;

    ConvJobs CJ;
    int jn = 0;
    auto CV = [&](const float* s, f16* d, int K, int N, int uc, float sc, int swz) {
        CJ.j[jn++] = ConvJob{s, d, K, N, uc, sc, swz};
    };
    CV(W_IN[0], Wl12_b1_s, 64, 64, 1, c_l1, 0);  CV(W_IN[2], Wl12_b1_s + 4096, 64, 64, 1, c_l1, 0);
    CV(W_IN[1], Wl12_b1_v, 64, 64, 1, c_l1, 0);  CV(W_IN[3], Wl12_b1_v + 4096, 64, 64, 1, c_l1, 0);
    CV(W_IN[13], Wl12_b2_s, 128, 128, 1, c128, 0); CV(W_IN[15], Wl12_b2_s + 16384, 128, 128, 1, c128, 0);
    CV(W_IN[14], Wl12_b2_v, 128, 128, 1, c128, 0); CV(W_IN[16], Wl12_b2_v + 16384, 128, 128, 1, c128, 0);
    CV(W_IN[4], Wtp_b1[0], 64, 128, 64, c1, 7);  CV(W_IN[5], Wtp_b1[1], 64, 128, 64, c1 * i3, 7);
    CV(W_IN[6], Wtp_b1[2], 64, 128, 64, c1, 7);  CV(W_IN[7], Wtp_b1[3], 64, 128, 64, c1, 7);
    CV(W_IN[17], Wtp_b2[0], 128, 128, 128, c2, 15); CV(W_IN[18], Wtp_b2[1], 128, 128, 128, c2 * i3, 15);
    CV(W_IN[19], Wtp_b2[2], 128, 128, 128, c2, 15); CV(W_IN[20], Wtp_b2[3], 128, 128, 128, c2, 15);
    CV(W_IN[8], Wg_b1_sg, 128, 128, 1, c128, 0);  CV(W_IN[9], Wg_b1_sg + 16384, 128, 128, 1, c128, 0);
    CV(W_IN[10], Wg_b1_v, 128, 128, 1, c128, 0);
    CV(W_IN[21], Wg_b2_sg, 128, 128, 1, c128, 0); CV(W_IN[22], Wg_b2_sg + 16384, 128, 128, 1, c128, 0);
    CV(W_IN[23], Wg_b2_v, 128, 128, 1, c128, 0);
    CV(W_IN[11], Wo_b1_s, 128, 128, 1, c128, 0);  CV(W_IN[12], Wo_b1_v, 128, 128, 1, c128, 0);
    CV(W_IN[24], Wo_b2_s, 128, 128, 1, c128, 0);  CV(W_IN[25], Wo_b2_v, 128, 128, 1, c128, 0);
    CV(W_IN[26], Wf_s, 128, 64, 1, c128, 0);      CV(W_IN[27], Wf_v, 128, 64, 1, c128, 0);
    convert_w<<<dim3(128, 1, 28), 256, 0, stream>>>(CJ);

    // compose folded weights (depends on convert_w; stream-ordered)
    {
        CompJobs CJ2;
        CJ2.j[0] = CompJob{Wo_b1_s, Wl12_b2_s, Wc_s_b12, 256};
        CJ2.j[1] = CompJob{Wo_b1_v, Wl12_b2_v, Wc_v_b12, 256};
        CJ2.j[2] = CompJob{Wo_b2_s, Wf_s, Wc_s_fin, 64};
        CJ2.j[3] = CompJob{Wo_b2_v, Wf_v, Wc_v_fin, 64};
        compose_w<<<dim3(256, 1, 4), 128, 0, stream>>>(CJ2);
    }

    x_to_planes<<<NB * 64 / 256, 256, 0, stream>>>(x, s_p, v_p[0], v_p[1], v_p[2]);

    auto SJ = [](const f16* A, const f16* W, void* out, int as, int os, int oc, int cs,
                 int mode, int Nj, int ny, const f16* Amul, int ms) {
        return SmallJob{A, W, (char*)out, as, os, oc, cs, mode, Nj, ny, Amul, ms,
                        nullptr, nullptr, nullptr, nullptr, 0};
    };

    f16* s12 = Breg;
    f16* v12[3]; for (int i = 0; i < 3; i++) v12[i] = Breg + (size_t)(1 + i) * NB * 128;
    f16* sg_gg = Ereg;
    f16* vl[3]; for (int i = 0; i < 3; i++) vl[i] = Ereg + 2 * S128 + i * S128;

    // ---- b1 l1+l2 ----
    {
        SmallJobs J;
        J.j[0] = SJ(s_p, Wl12_b1_s, s12, 64, 128, 0, 1, 0, 128, 1, nullptr, 0);
        for (int i = 0; i < 3; i++) J.j[1 + i] = SJ(v_p[i], Wl12_b1_v, v12[i], 64, 128, 0, 1, 0, 128, 1, nullptr, 0);
        small_gemm<64><<<dim3(128, 1, 4), 256, 0, stream>>>(J);
    }
    // ---- b1 tensor product ----
    {
        TpJobs J;
        J.j[0] = TpJob{s12, s12 + 64, Wtp_b1[0], Part + 0 * S128, 128, 128};
        for (int i = 0; i < 3; i++) J.j[1 + i] = TpJob{v12[i], v12[i] + 64, Wtp_b1[1], Part + (1 + i) * S128, 128, 128};
        for (int i = 0; i < 3; i++) J.j[4 + i] = TpJob{s12, v12[i] + 64, Wtp_b1[2], Part + (4 + i) * S128, 128, 128};
        for (int i = 0; i < 3; i++) J.j[7 + i] = TpJob{v12[i], s12 + 64, Wtp_b1[3], Part + (7 + i) * S128, 128, 128};
        tp_unit<64><<<dim3(64, 2, 10), 256, 0, stream>>>(J);
    }
    // ---- b1 gate (tp_reduce fused into A-load) ----
    {
        SmallJobs J;
        J.j[0] = SmallJob{nullptr, Wg_b1_sg, (char*)sg_gg, 128, 256, 0, 1, 1, 256, 2, nullptr, 0,
                          Part + 0 * S128, Part + 1 * S128, Part + 2 * S128, Part + 3 * S128, 4};
        for (int i = 0; i < 3; i++)
            J.j[1 + i] = SmallJob{nullptr, Wg_b1_v, (char*)vl[i], 128, 128, 0, 1, 0, 128, 1, nullptr, 0,
                                  Part + (4 + i) * S128, Part + (7 + i) * S128, nullptr, nullptr, 2};
        small_gemm<128><<<dim3(128, 2, 4), 256, 0, stream>>>(J);
    }
    f16* s12b = Breg;
    f16* v12b[3]; for (int i = 0; i < 3; i++) v12b[i] = Breg + (size_t)(1 + i) * NB * 256;
    // ---- b1 o-lin + b2 l1+l2, folded via composed weights (R6) ----
    {
        SmallJobs J;
        J.j[0] = SJ(sg_gg, Wc_s_b12, s12b, 256, 256, 0, 1, 0, 256, 2, nullptr, 0);
        for (int i = 0; i < 3; i++)
            J.j[1 + i] = SJ(vl[i], Wc_v_b12, v12b[i], 128, 256, 0, 1, 0, 256, 2, sg_gg + 128, 256);
        small_gemm<128><<<dim3(128, 2, 4), 256, 0, stream>>>(J);
    }
    // ---- b2 tensor product ----
    {
        TpJobs J;
        J.j[0] = TpJob{s12b, s12b + 128, Wtp_b2[0], Part + 0 * S128, 256, 256};
        for (int i = 0; i < 3; i++) J.j[1 + i] = TpJob{v12b[i], v12b[i] + 128, Wtp_b2[1], Part + (1 + i) * S128, 256, 256};
        for (int i = 0; i < 3; i++) J.j[4 + i] = TpJob{s12b, v12b[i] + 128, Wtp_b2[2], Part + (4 + i) * S128, 256, 256};
        for (int i = 0; i < 3; i++) J.j[7 + i] = TpJob{v12b[i], s12b + 128, Wtp_b2[3], Part + (7 + i) * S128, 256, 256};
        tp_unit<128><<<dim3(64, 2, 10), 256, 0, stream>>>(J);
    }
    // ---- b2 gate (tp_reduce fused) ----
    {
        SmallJobs J;
        J.j[0] = SmallJob{nullptr, Wg_b2_sg, (char*)sg_gg, 128, 256, 0, 1, 1, 256, 2, nullptr, 0,
                          Part + 0 * S128, Part + 1 * S128, Part + 2 * S128, Part + 3 * S128, 4};
        for (int i = 0; i < 3; i++)
            J.j[1 + i] = SmallJob{nullptr, Wg_b2_v, (char*)vl[i], 128, 128, 0, 1, 0, 128, 1, nullptr, 0,
                                  Part + (4 + i) * S128, Part + (7 + i) * S128, nullptr, nullptr, 2};
        small_gemm<128><<<dim3(128, 2, 4), 256, 0, stream>>>(J);
    }
    // ---- b2 o-lin + final lin, folded via composed weights -> d_out ----
    {
        SmallJobs J;
        J.j[0] = SJ(sg_gg, Wc_s_fin, d_out, 256, 256, 0, 1, 2, 64, 1, nullptr, 0);
        for (int i = 0; i < 3; i++)
            J.j[1 + i] = SJ(vl[i], Wc_v_fin, d_out, 128, 256, 64 + i, 3, 2, 64, 1, sg_gg + 128, 256);
        small_gemm<128><<<dim3(128, 1, 4), 256, 0, stream>>>(J);
    }
}